// Round 14
// baseline (726.222 us; speedup 1.0000x reference)
//
#include <hip/hip_runtime.h>
#include <cmath>

#define HID 128

typedef __attribute__((ext_vector_type(8))) short bf16x8;
typedef __attribute__((ext_vector_type(4))) float f32x4;

__device__ inline unsigned short f2bf_rne(float f) {
  unsigned int b = __float_as_uint(f);
  return (unsigned short)((b + 0x7fffu + ((b >> 16) & 1u)) >> 16);
}
__device__ inline float bf2f(unsigned int u) { return __uint_as_float(u << 16); }

// dst-space: f:0 | rs:100000 | rd:120000 | hrd:170000 ; NDTOT=220000
#define NDTOT 220000
#define ETOT 4000000
#define BSH 8            // 256 dst per bucket
#define BDST 256
#define NB 860           // ceil(NDTOT/BDST)
#define BCAP 5376        // fixed bucket capacity (mean 4654, sigma 68 -> 10.6 sigma)
#define EPB 16384        // edges per binning block
#define NBINBLK 245      // ceil(ETOT/EPB)

// ---------------- utility kernels ----------------

// zero bfill[NB], asmax[16], feats[384] in one launch
__global__ void fill_z_kernel(int* __restrict__ bfill, unsigned int* __restrict__ asmax,
                              float* __restrict__ feats) {
  int i = blockIdx.x * 256 + threadIdx.x;
  if (i < NB) bfill[i] = 0;
  if (i < 16) asmax[i] = 0u;
  if (i < 384) feats[i] = 0.f;
}

// fp32 -> bf16 (RNE) for all three states in one launch; item = 8 floats
__global__ void f2bf_all_kernel(const float* __restrict__ xa, const float* __restrict__ xrs,
                                const float* __restrict__ xrd, unsigned short* __restrict__ oa,
                                unsigned short* __restrict__ ors, unsigned short* __restrict__ ord) {
  int i = blockIdx.x * 256 + threadIdx.x;
  const float* in; unsigned short* out; int li;
  if (i < 1600000)      { in = xa;  out = oa;  li = i; }
  else if (i < 1920000) { in = xrs; out = ors; li = i - 1600000; }
  else if (i < 2720000) { in = xrd; out = ord; li = i - 1920000; }
  else return;
  const float4* p4 = reinterpret_cast<const float4*>(in) + (size_t)li * 2;
  float4 v0 = p4[0], v1 = p4[1];
  float vv[8] = {v0.x, v0.y, v0.z, v0.w, v1.x, v1.y, v1.z, v1.w};
  unsigned int r[8];
#pragma unroll
  for (int j = 0; j < 8; ++j) r[j] = f2bf_rne(vv[j]);
  uint4 o;
  o.x = r[0] | (r[1] << 16);
  o.y = r[2] | (r[3] << 16);
  o.z = r[4] | (r[5] << 16);
  o.w = r[6] | (r[7] << 16);
  reinterpret_cast<uint4*>(out)[li] = o;
}

// pack 9 x 128x128 fp32 W (row-major [k][col]) into MFMA B-fragment order, bf16.
__global__ void pack_w_kernel(const float* __restrict__ Wsrc8, const float* __restrict__ W_ln,
                              unsigned short* __restrict__ Wp) {
  int g = blockIdx.y;
  const float* W = (g < 8) ? (Wsrc8 + (size_t)g * 16384) : W_ln;
  unsigned short* op = Wp + (size_t)g * 16384;
  int o = blockIdx.x * 256 + threadIdx.x;
  if (o >= 16384) return;
  int j = o & 7;
  int lane = (o >> 3) & 63;
  int kk = (o >> 9) & 3;
  int ct = (o >> 11) & 3;
  int half = (o >> 13) & 1;
  int k = kk * 32 + ((lane >> 4) * 8) + j;
  int col = half * 64 + ct * 16 + (lane & 15);
  op[o] = f2bf_rne(W[k * 128 + col]);
}

// v[g][k] = sum_c W[g][k][c] * a[g][c]; blockIdx.y: 0 -> (Wsrc,att_src,vs), 1 -> (Wdst,att_dst,vd)
__global__ void compute_v2_kernel(const float* __restrict__ Wsrc, const float* __restrict__ Wdst,
                                  const float* __restrict__ as_, const float* __restrict__ ad_,
                                  float* __restrict__ vs, float* __restrict__ vd) {
  int g = blockIdx.x, k = threadIdx.x;
  const float* W = (blockIdx.y ? Wdst : Wsrc) + g * 16384;
  const float* a = (blockIdx.y ? ad_ : as_) + g * 128;
  float* v = (blockIdx.y ? vd : vs) + g * 128;
  float s = 0.f;
  for (int c = 0; c < 128; ++c) s = fmaf(W[k * 128 + c], a[c], s);
  v[k] = s;
}

// ---------------- fused alpha matvec + per-layer max|alpha_src| ----------------
__device__ inline const float* pick_vec(int r, const float* vs, const float* vd, int L) {
  switch (r) {
    case 0: return vs + (0 + L) * 128;   // af_s
    case 1: return vd + (0 + L) * 128;   // af_d
    case 2: return vs + (2 + L) * 128;   // ars_s
    case 3: return vs + (6 + L) * 128;   // ahrd_s
    case 4: return vs + (4 + L) * 128;   // ard_s
    case 5: return vd + (4 + L) * 128;   // ard_d
    case 6: return vd + (6 + L) * 128;   // ahrd_d
    default: return vd + (2 + L) * 128;  // ars_d
  }
}

__global__ __launch_bounds__(256) void matvec_fused_kernel(
    const unsigned short* __restrict__ xa, const unsigned short* __restrict__ xrd,
    const unsigned short* __restrict__ xrs, const float* __restrict__ vs,
    const float* __restrict__ vd, int L, float* __restrict__ af_s, float* __restrict__ af_d,
    float* __restrict__ ars_s, float* __restrict__ ahrd_s, float* __restrict__ ard_s,
    float* __restrict__ ard_d, float* __restrict__ ahrd_d, float* __restrict__ ars_d,
    unsigned int* __restrict__ asmax_L) {  // asmax_u + L*4 ; [0]=af_s [1]=ars_s [2]=ahrd_s [3]=ard_s
  __shared__ float vl[11][128];
  __shared__ unsigned int lmax[4];
  int tid = threadIdx.x;
  if (tid < 4) lmax[tid] = 0u;
  for (int i = tid; i < 1024; i += 256) {
    int r = i >> 7;
    vl[r][i & 127] = pick_vec(r, vs, vd, L)[i & 127];
  }
  for (int i = tid; i < 384; i += 256) vl[8 + (i >> 7)][i & 127] = 0.f;
  __syncthreads();
  int wave = tid >> 6, lane = tid & 63;
  int sub = lane >> 4, li = lane & 15;
  int row = blockIdx.x * 16 + wave * 4 + sub;
  bool active = row < 170000;
  float a0 = 0.f, a1 = 0.f, a2 = 0.f, a3 = 0.f;
  const unsigned short* X = xa;
  int lrow = 0, vbase = 0;
  if (active) {
    if (row < 100000)      { X = xa;  lrow = row;          vbase = 0; }
    else if (row < 150000) { X = xrd; lrow = row - 100000; vbase = 4; }
    else                   { X = xrs; lrow = row - 150000; vbase = 7; }
    const uint4 xv = *reinterpret_cast<const uint4*>(X + (size_t)lrow * 128 + li * 8);
    float f[8];
    f[0] = bf2f(xv.x & 0xffffu); f[1] = bf2f(xv.x >> 16);
    f[2] = bf2f(xv.y & 0xffffu); f[3] = bf2f(xv.y >> 16);
    f[4] = bf2f(xv.z & 0xffffu); f[5] = bf2f(xv.z >> 16);
    f[6] = bf2f(xv.w & 0xffffu); f[7] = bf2f(xv.w >> 16);
#pragma unroll
    for (int q = 0; q < 8; ++q) {
      int col = li * 8 + q;
      a0 = fmaf(f[q], vl[vbase][col], a0);
      a1 = fmaf(f[q], vl[vbase + 1][col], a1);
      a2 = fmaf(f[q], vl[vbase + 2][col], a2);
      a3 = fmaf(f[q], vl[vbase + 3][col], a3);
    }
#pragma unroll
    for (int off = 8; off >= 1; off >>= 1) {
      a0 += __shfl_xor(a0, off);
      a1 += __shfl_xor(a1, off);
      a2 += __shfl_xor(a2, off);
      a3 += __shfl_xor(a3, off);
    }
    if (li == 0) {
      if (row < 100000) {
        af_s[lrow] = a0; af_d[lrow] = a1; ars_s[lrow] = a2; ahrd_s[lrow] = a3;
        atomicMax(&lmax[0], __float_as_uint(fabsf(a0)));
        atomicMax(&lmax[1], __float_as_uint(fabsf(a2)));
        atomicMax(&lmax[2], __float_as_uint(fabsf(a3)));
      } else if (row < 150000) {
        ard_s[lrow] = a0; ard_d[lrow] = a1; ahrd_d[lrow] = a2;
        atomicMax(&lmax[3], __float_as_uint(fabsf(a0)));
      } else {
        ars_d[lrow] = a0;
      }
    }
  }
  __syncthreads();
  if (tid < 4 && lmax[tid]) atomicMax(&asmax_L[tid], lmax[tid]);
}

// ---------------- CSR build: fixed-capacity buckets (no hist, no scan) ----------------

__device__ inline void decode_edge(int e, const int* __restrict__ s0, const int* __restrict__ d0,
                                   const int* __restrict__ s1, const int* __restrict__ d1,
                                   const int* __restrict__ s2, const int* __restrict__ d2,
                                   const int* __restrict__ s3, const int* __restrict__ d3,
                                   int& src, int& gd) {
  const int* sp; const int* dp; int base, doff;
  if (e < 1600000)      { sp = s0; dp = d0; base = 0;       doff = 0; }
  else if (e < 2400000) { sp = s1; dp = d1; base = 1600000; doff = 100000; }
  else if (e < 3200000) { sp = s2; dp = d2; base = 2400000; doff = 120000; }
  else                  { sp = s3; dp = d3; base = 3200000; doff = 170000; }
  int i = e - base;
  src = sp[i];
  gd = doff + dp[i];
}

// pass 1: scatter packed (local_dst<<24 | src) into fixed-capacity bucket regions
__global__ __launch_bounds__(256) void bin_scatter_kernel(
    const int* __restrict__ s0, const int* __restrict__ d0, const int* __restrict__ s1,
    const int* __restrict__ d1, const int* __restrict__ s2, const int* __restrict__ d2,
    const int* __restrict__ s3, const int* __restrict__ d3,
    int* __restrict__ bfill, unsigned int* __restrict__ pair_buf) {
  __shared__ int lh[NB];
  __shared__ int lbase[NB];
  for (int i = threadIdx.x; i < NB; i += 256) lh[i] = 0;
  __syncthreads();
  int e0 = blockIdx.x * EPB;
  for (int i = 0; i < EPB; i += 256) {
    int e = e0 + i + threadIdx.x;
    if (e < ETOT) {
      const int* dp; int base, doff;
      if (e < 1600000)      { dp = d0; base = 0;       doff = 0; }
      else if (e < 2400000) { dp = d1; base = 1600000; doff = 100000; }
      else if (e < 3200000) { dp = d2; base = 2400000; doff = 120000; }
      else                  { dp = d3; base = 3200000; doff = 170000; }
      atomicAdd(&lh[(doff + dp[e - base]) >> BSH], 1);
    }
  }
  __syncthreads();
  for (int i = threadIdx.x; i < NB; i += 256) {
    int c = lh[i];
    if (c) lbase[i] = i * BCAP + atomicAdd(&bfill[i], c);
    lh[i] = 0;  // reuse as cursor
  }
  __syncthreads();
  for (int i = 0; i < EPB; i += 256) {
    int e = e0 + i + threadIdx.x;
    if (e < ETOT) {
      int src, gd;
      decode_edge(e, s0, d0, s1, d1, s2, d2, s3, d3, src, gd);
      int b = gd >> BSH;
      int pos = atomicAdd(&lh[b], 1);
      pair_buf[lbase[b] + pos] = ((unsigned)(gd & (BDST - 1)) << 24) | (unsigned)src;
    }
  }
}

// pass 2: per-bucket — local hist/scan builds rbeg/rend, then in-window scatter
__global__ __launch_bounds__(256) void bucket_build_kernel(
    const unsigned int* __restrict__ pair_buf, const int* __restrict__ bfill,
    int* __restrict__ rbeg, int* __restrict__ rend, int* __restrict__ csr_cat) {
  __shared__ int lcnt[BDST];
  __shared__ int lrp[BDST + 1];
  int b = blockIdx.x;
  int d0 = b << BSH;
  int nd = min(BDST, NDTOT - d0);
  int base = b * BCAP, end = base + bfill[b];
  for (int i = threadIdx.x; i < nd; i += 256) lcnt[i] = 0;
  __syncthreads();
  for (int j = base + threadIdx.x; j < end; j += 256)
    atomicAdd(&lcnt[pair_buf[j] >> 24], 1);
  __syncthreads();
  if (threadIdx.x == 0) {
    int run = base;
    for (int i = 0; i < nd; ++i) { lrp[i] = run; run += lcnt[i]; }
    lrp[nd] = run;
  }
  __syncthreads();
  for (int i = threadIdx.x; i < nd; i += 256) {
    rbeg[d0 + i] = lrp[i];
    rend[d0 + i] = lrp[i + 1];
  }
  for (int i = threadIdx.x; i < nd; i += 256) lcnt[i] = 0;
  __syncthreads();
  for (int j = base + threadIdx.x; j < end; j += 256) {
    unsigned int pr = pair_buf[j];
    int ld = pr >> 24;
    int pos = lrp[ld] + atomicAdd(&lcnt[ld], 1);
    csr_cat[pos] = (int)(pr & 0xFFFFFFu);
  }
}

// ---------------- fused GAT aggregation, 4-deep pipelined gather (R10/R12 proven) ----------------
// p = exp(e - mhat), mhat = lrelu(max|as| + ad[d]) >= all e
#define ACC8(xv, wgt)                                   \
  do {                                                  \
    a[0] = fmaf(wgt, bf2f((xv).x & 0xffffu), a[0]);     \
    a[1] = fmaf(wgt, bf2f((xv).x >> 16), a[1]);         \
    a[2] = fmaf(wgt, bf2f((xv).y & 0xffffu), a[2]);     \
    a[3] = fmaf(wgt, bf2f((xv).y >> 16), a[3]);         \
    a[4] = fmaf(wgt, bf2f((xv).z & 0xffffu), a[4]);     \
    a[5] = fmaf(wgt, bf2f((xv).z >> 16), a[5]);         \
    a[6] = fmaf(wgt, bf2f((xv).w & 0xffffu), a[6]);     \
    a[7] = fmaf(wgt, bf2f((xv).w >> 16), a[7]);         \
  } while (0)

__global__ __launch_bounds__(256) void gat_aggr_fused(
    const int* __restrict__ rbeg, const int* __restrict__ rend,
    const int* __restrict__ csr_cat,
    const float* __restrict__ af_s, const float* __restrict__ af_d,
    const float* __restrict__ ars_s, const float* __restrict__ ars_d,
    const float* __restrict__ ard_s, const float* __restrict__ ard_d,
    const float* __restrict__ ahrd_s, const float* __restrict__ ahrd_d,
    const unsigned int* __restrict__ asmax, const unsigned short* __restrict__ xa,
    const unsigned short* __restrict__ xrd, unsigned short* __restrict__ aggh) {
  __shared__ float2 sp[4][64];
  int wave = threadIdx.x >> 6, lane = threadIdx.x & 63;
  int g = lane >> 4, li = lane & 15;
  int gd = blockIdx.x * 4 + wave;
  if (gd >= NDTOT) return;
  const float* as_; const float* ad_; const unsigned short* Xh; int midx, d;
  if (gd < 100000)      { as_ = af_s;  ad_ = af_d;  Xh = xa;  midx = 0; d = gd; }
  else if (gd < 120000) { as_ = ars_s; ad_ = ars_d; Xh = xa;  midx = 1; d = gd - 100000; }
  else if (gd < 170000) { as_ = ard_s; ad_ = ard_d; Xh = xrd; midx = 3; d = gd - 120000; }
  else                  { as_ = ahrd_s; ad_ = ahrd_d; Xh = xa; midx = 2; d = gd - 170000; }
  int beg = rbeg[gd], end = rend[gd];
  float ad = ad_[d];
  float t0 = __uint_as_float(asmax[midx]) + ad;
  float mh = t0 > 0.f ? t0 : 0.2f * t0;
  float z = 0.f;
  float a[8] = {};
  for (int c0 = beg; c0 < end; c0 += 64) {
    int j = c0 + lane;
    int s = 0;
    float p = 0.f;
    if (j < end) {
      s = csr_cat[j];
      float t = as_[s] + ad;
      float e = t > 0.f ? t : 0.2f * t;
      p = __expf(e - mh);
      z += p;
    }
    sp[wave][lane] = make_float2(__int_as_float(s), p);
    asm volatile("s_waitcnt lgkmcnt(0)" ::: "memory");
    int cnt = min(64, end - c0);
    // subgroup g handles edges g, g+4, g+8, ... ; 4 edges pipelined per iter
    for (int k = g; k < cnt; k += 16) {
      float2 w0 = sp[wave][k];
      float2 w1 = (k + 4 < cnt) ? sp[wave][k + 4] : make_float2(0.f, 0.f);
      float2 w2 = (k + 8 < cnt) ? sp[wave][k + 8] : make_float2(0.f, 0.f);
      float2 w3 = (k + 12 < cnt) ? sp[wave][k + 12] : make_float2(0.f, 0.f);
      // masked edges -> row 0 with weight 0 (branch-free, safe)
      const uint4 x0 = *reinterpret_cast<const uint4*>(
          Xh + (size_t)(unsigned)__float_as_int(w0.x) * 128 + li * 8);
      const uint4 x1 = *reinterpret_cast<const uint4*>(
          Xh + (size_t)(unsigned)__float_as_int(w1.x) * 128 + li * 8);
      const uint4 x2 = *reinterpret_cast<const uint4*>(
          Xh + (size_t)(unsigned)__float_as_int(w2.x) * 128 + li * 8);
      const uint4 x3 = *reinterpret_cast<const uint4*>(
          Xh + (size_t)(unsigned)__float_as_int(w3.x) * 128 + li * 8);
      ACC8(x0, w0.y);
      ACC8(x1, w1.y);
      ACC8(x2, w2.y);
      ACC8(x3, w3.y);
    }
  }
#pragma unroll
  for (int off = 32; off >= 1; off >>= 1) z += __shfl_xor(z, off);
#pragma unroll
  for (int i = 0; i < 8; ++i) {
    a[i] += __shfl_xor(a[i], 32);
    a[i] += __shfl_xor(a[i], 16);
  }
  if (g == 0) {
    float inv = 1.f / fmaxf(z, 1e-16f);
    uint4 o;
    o.x = (unsigned)f2bf_rne(a[0] * inv) | ((unsigned)f2bf_rne(a[1] * inv) << 16);
    o.y = (unsigned)f2bf_rne(a[2] * inv) | ((unsigned)f2bf_rne(a[3] * inv) << 16);
    o.z = (unsigned)f2bf_rne(a[4] * inv) | ((unsigned)f2bf_rne(a[5] * inv) << 16);
    o.w = (unsigned)f2bf_rne(a[6] * inv) | ((unsigned)f2bf_rne(a[7] * inv) << 16);
    *reinterpret_cast<uint4*>(aggh + (size_t)gd * 128 + li * 8) = o;
  }
}

// ---------------- fused MFMA GEMM over the 3 per-layer GEMMs ----------------
// blocks: [0,782) act | [782,939) rs | [939,1330) rd (two-input K=256)
__global__ __launch_bounds__(256) void gemm_all_kernel(
    const unsigned short* __restrict__ aggh, const unsigned short* __restrict__ wpack,
    const float* __restrict__ b_gat, int L, unsigned short* __restrict__ ya,
    unsigned short* __restrict__ yrs, unsigned short* __restrict__ yrd) {
  int bx = blockIdx.x;
  const unsigned short *X1, *X2 = nullptr, *Wp1, *Wp2 = nullptr;
  const float *bias1, *bias2 = nullptr;
  unsigned short* Y;
  int N, r0;
  if (bx < 782) {
    int gg = 0 + L;
    X1 = aggh; Wp1 = wpack + (size_t)gg * 16384; bias1 = b_gat + gg * 128;
    Y = ya; N = 100000; r0 = bx * 128;
  } else if (bx < 939) {
    int gg = 2 + L;
    X1 = aggh + (size_t)100000 * 128; Wp1 = wpack + (size_t)gg * 16384;
    bias1 = b_gat + gg * 128;
    Y = yrs; N = 20000; r0 = (bx - 782) * 128;
  } else {
    int g2 = 4 + L, g3 = 6 + L;
    X1 = aggh + (size_t)120000 * 128; Wp1 = wpack + (size_t)g2 * 16384;
    bias1 = b_gat + g2 * 128;
    X2 = aggh + (size_t)170000 * 128; Wp2 = wpack + (size_t)g3 * 16384;
    bias2 = b_gat + g3 * 128;
    Y = yrd; N = 50000; r0 = (bx - 939) * 128;
  }
  int wid = threadIdx.x >> 6, lane = threadIdx.x & 63;
  int half = blockIdx.y;
  int rr0 = r0 + wid * 32;
  int lr = lane & 15, gk = lane >> 4;
  f32x4 acc[2][4];
#pragma unroll
  for (int rt = 0; rt < 2; ++rt)
#pragma unroll
    for (int ct = 0; ct < 4; ++ct) acc[rt][ct] = (f32x4){0.f, 0.f, 0.f, 0.f};
  int row0 = rr0 + lr, row1 = rr0 + 16 + lr;
  int nph = X2 ? 2 : 1;
  for (int ph = 0; ph < nph; ++ph) {
    const unsigned short* X = ph ? X2 : X1;
    const unsigned short* Wp = ph ? Wp2 : Wp1;
    bf16x8 b[4][4];
#pragma unroll
    for (int ct = 0; ct < 4; ++ct)
#pragma unroll
      for (int kk = 0; kk < 4; ++kk)
        b[ct][kk] = *reinterpret_cast<const bf16x8*>(Wp + ((((half * 4 + ct) * 4 + kk) * 64 + lane) << 3));
#pragma unroll
    for (int kk = 0; kk < 4; ++kk) {
      bf16x8 a0 = {}, a1 = {};
      if (row0 < N) a0 = *reinterpret_cast<const bf16x8*>(X + (size_t)row0 * 128 + kk * 32 + gk * 8);
      if (row1 < N) a1 = *reinterpret_cast<const bf16x8*>(X + (size_t)row1 * 128 + kk * 32 + gk * 8);
#pragma unroll
      for (int ct = 0; ct < 4; ++ct) {
        acc[0][ct] = __builtin_amdgcn_mfma_f32_16x16x32_bf16(a0, b[ct][kk], acc[0][ct], 0, 0, 0);
        acc[1][ct] = __builtin_amdgcn_mfma_f32_16x16x32_bf16(a1, b[ct][kk], acc[1][ct], 0, 0, 0);
      }
    }
  }
#pragma unroll
  for (int rt = 0; rt < 2; ++rt)
#pragma unroll
    for (int ct = 0; ct < 4; ++ct) {
      int col = half * 64 + ct * 16 + lr;
      float bcol = bias1[col] + (bias2 ? bias2[col] : 0.f);
#pragma unroll
      for (int reg = 0; reg < 4; ++reg) {
        int row = rr0 + rt * 16 + gk * 4 + reg;
        if (row < N) {
          float o = acc[rt][ct][reg] + bcol;
          Y[(size_t)row * 128 + col] = f2bf_rne(fmaxf(o, 0.f));
        }
      }
    }
}

// ---------------- fused MFMA head over the 3 node types ----------------
__global__ __launch_bounds__(256) void head_fused_kernel(
    const unsigned short* __restrict__ xa, const unsigned short* __restrict__ xrs,
    const unsigned short* __restrict__ xrd, const unsigned short* __restrict__ Wp,
    const float* __restrict__ bias, float* __restrict__ feat) {
  __shared__ float cs[64];
  int bx = blockIdx.x;
  const unsigned short* X; float* f; int N, bx0;
  if (bx < 196)      { X = xa;  f = feat;       N = 100000; bx0 = bx; }
  else if (bx < 236) { X = xrs; f = feat + 128; N = 20000;  bx0 = bx - 196; }
  else               { X = xrd; f = feat + 256; N = 50000;  bx0 = bx - 236; }
  int wid = threadIdx.x >> 6, lane = threadIdx.x & 63;
  int half = blockIdx.y;
  int lr = lane & 15, gk = lane >> 4;
  if (threadIdx.x < 64) cs[threadIdx.x] = 0.f;
  __syncthreads();
  bf16x8 b[4][4];
#pragma unroll
  for (int ct = 0; ct < 4; ++ct)
#pragma unroll
    for (int kk = 0; kk < 4; ++kk)
      b[ct][kk] = *reinterpret_cast<const bf16x8*>(Wp + ((((half * 4 + ct) * 4 + kk) * 64 + lane) << 3));
  float colsum[4] = {0.f, 0.f, 0.f, 0.f};
  for (int c = 0; c < 4; ++c) {
    int r0 = bx0 * 512 + c * 128 + wid * 32;
    if (r0 >= N) break;
    f32x4 acc[2][4];
#pragma unroll
    for (int rt = 0; rt < 2; ++rt)
#pragma unroll
      for (int ct = 0; ct < 4; ++ct) acc[rt][ct] = (f32x4){0.f, 0.f, 0.f, 0.f};
    int row0 = r0 + lr, row1 = r0 + 16 + lr;
#pragma unroll
    for (int kk = 0; kk < 4; ++kk) {
      bf16x8 a0 = {}, a1 = {};
      if (row0 < N) a0 = *reinterpret_cast<const bf16x8*>(X + (size_t)row0 * 128 + kk * 32 + gk * 8);
      if (row1 < N) a1 = *reinterpret_cast<const bf16x8*>(X + (size_t)row1 * 128 + kk * 32 + gk * 8);
#pragma unroll
      for (int ct = 0; ct < 4; ++ct) {
        acc[0][ct] = __builtin_amdgcn_mfma_f32_16x16x32_bf16(a0, b[ct][kk], acc[0][ct], 0, 0, 0);
        acc[1][ct] = __builtin_amdgcn_mfma_f32_16x16x32_bf16(a1, b[ct][kk], acc[1][ct], 0, 0, 0);
      }
    }
#pragma unroll
    for (int rt = 0; rt < 2; ++rt)
#pragma unroll
      for (int ct = 0; ct < 4; ++ct) {
        float bcol = bias[half * 64 + ct * 16 + lr];
#pragma unroll
        for (int reg = 0; reg < 4; ++reg) {
          int row = r0 + rt * 16 + gk * 4 + reg;
          if (row < N) colsum[ct] += fmaxf(acc[rt][ct][reg] + bcol, 0.f);
        }
      }
  }
#pragma unroll
  for (int ct = 0; ct < 4; ++ct) {
    float v = colsum[ct];
    v += __shfl_xor(v, 16);
    v += __shfl_xor(v, 32);
    if (gk == 0) atomicAdd(&cs[ct * 16 + lr], v);
  }
  __syncthreads();
  if (threadIdx.x < 64) atomicAdd(&f[half * 64 + threadIdx.x], cs[threadIdx.x]);
}

__global__ void final_fc_kernel(const float* __restrict__ fa, const float* __restrict__ frs,
                                const float* __restrict__ frd, const float* __restrict__ Wfc,
                                const float* __restrict__ bfc, float* __restrict__ out) {
  __shared__ float pooled[128];
  int t = threadIdx.x;
  if (t < 128)
    pooled[t] = (fa[t] * (1.f / 100000.f) + frs[t] * (1.f / 20000.f) + frd[t] * (1.f / 50000.f)) *
                (1.f / 3.f);
  __syncthreads();
  if (t < 64) {
    float s = bfc[t];
    for (int c = 0; c < 128; ++c) s = fmaf(pooled[c], Wfc[c * 64 + t], s);
    out[t] = s;
  }
}

// ---------------- orchestration ----------------

extern "C" void kernel_launch(void* const* d_in, const int* in_sizes, int n_in,
                              void* d_out, int out_size, void* d_ws, size_t ws_size,
                              hipStream_t stream) {
  const int N_ACT = 100000, N_RS = 20000, N_RD = 50000;

  const float* x_act = (const float*)d_in[0];
  const float* x_rs = (const float*)d_in[1];
  const float* x_rd = (const float*)d_in[2];
  const int* ef_src = (const int*)d_in[3];
  const int* ef_dst = (const int*)d_in[4];
  const int* ers_src = (const int*)d_in[5];
  const int* ers_dst = (const int*)d_in[6];
  const int* erd_src = (const int*)d_in[7];
  const int* erd_dst = (const int*)d_in[8];
  const int* ehrd_src = (const int*)d_in[9];
  const int* ehrd_dst = (const int*)d_in[10];
  const float* Wsrc = (const float*)d_in[11];
  const float* Wdst = (const float*)d_in[12];
  const float* att_src = (const float*)d_in[13];
  const float* att_dst = (const float*)d_in[14];
  const float* b_gat = (const float*)d_in[15];
  const float* W_ln = (const float*)d_in[16];
  const float* b_ln = (const float*)d_in[17];
  const float* W_fc = (const float*)d_in[18];
  const float* b_fc = (const float*)d_in[19];
  float* out = (float*)d_out;

  // ---- workspace layout (~175 MB) ----
  float* w = (float*)d_ws;
  float* af_s = w;   w += N_ACT;
  float* af_d = w;   w += N_ACT;
  float* ars_s = w;  w += N_ACT;
  float* ahrd_s = w; w += N_ACT;
  float* ard_s = w;  w += N_RD;
  float* ard_d = w;  w += N_RD;
  float* ahrd_d = w; w += N_RD;
  float* ars_d = w;  w += N_RS;
  float* vs = w;    w += 1024;
  float* vd = w;    w += 1024;
  float* feats = w; w += 384;
  unsigned int* asmax_u = (unsigned int*)w; w += 16;
  unsigned short* xa0 = (unsigned short*)w;   w += (size_t)N_ACT * 64;
  unsigned short* xa1 = (unsigned short*)w;   w += (size_t)N_ACT * 64;
  unsigned short* xrd0 = (unsigned short*)w;  w += (size_t)N_RD * 64;
  unsigned short* xrd1 = (unsigned short*)w;  w += (size_t)N_RD * 64;
  unsigned short* xrs_b = (unsigned short*)w; w += (size_t)N_RS * 64;
  unsigned short* aggh = (unsigned short*)w;  w += (size_t)NDTOT * 64;  // concat agg
  unsigned short* wpack = (unsigned short*)w; w += (9 * 16384) / 2;
  int* ip = (int*)w;
  unsigned int* pair_buf = (unsigned int*)ip; ip += NB * BCAP;  // packed (ld<<24)|src
  int* csr_cat = ip;          ip += NB * BCAP;
  int* rbeg = ip;             ip += NDTOT;
  int* rend = ip;             ip += NDTOT;
  int* bfill = ip;            ip += NB;

  // ---- init + CSR build: fixed-capacity buckets ----
  fill_z_kernel<<<(NB + 255) / 256, 256, 0, stream>>>(bfill, asmax_u, feats);
  bin_scatter_kernel<<<NBINBLK, 256, 0, stream>>>(
      ef_src, ef_dst, ers_src, ers_dst, erd_src, erd_dst, ehrd_src, ehrd_dst,
      bfill, pair_buf);
  bucket_build_kernel<<<NB, 256, 0, stream>>>(pair_buf, bfill, rbeg, rend, csr_cat);

  // ---- one-time: attention vectors, packed weights, bf16 states ----
  compute_v2_kernel<<<dim3(8, 2), 128, 0, stream>>>(Wsrc, Wdst, att_src, att_dst, vs, vd);
  pack_w_kernel<<<dim3(64, 9), 256, 0, stream>>>(Wsrc, W_ln, wpack);
  f2bf_all_kernel<<<(2720000 + 255) / 256, 256, 0, stream>>>(x_act, x_rs, x_rd,
                                                             xa0, xrs_b, xrd0);

  const unsigned short* xa = xa0;
  unsigned short* xa_nxt = xa1;
  const unsigned short* xrd = xrd0;
  unsigned short* xrd_nxt = xrd1;

  for (int L = 0; L < 2; ++L) {
    matvec_fused_kernel<<<(170000 + 15) / 16, 256, 0, stream>>>(
        xa, xrd, xrs_b, vs, vd, L, af_s, af_d, ars_s, ahrd_s, ard_s, ard_d, ahrd_d, ars_d,
        asmax_u + L * 4);

    gat_aggr_fused<<<(NDTOT + 3) / 4, 256, 0, stream>>>(
        rbeg, rend, csr_cat, af_s, af_d, ars_s, ars_d, ard_s, ard_d, ahrd_s, ahrd_d,
        asmax_u + L * 4, xa, xrd, aggh);

    gemm_all_kernel<<<dim3(1330, 2), 256, 0, stream>>>(aggh, wpack, b_gat, L,
                                                       xa_nxt, xrs_b, xrd_nxt);

    const unsigned short* t1 = xa; xa = xa_nxt; xa_nxt = (unsigned short*)t1;
    const unsigned short* t2 = xrd; xrd = xrd_nxt; xrd_nxt = (unsigned short*)t2;
  }

  head_fused_kernel<<<dim3(334, 2), 256, 0, stream>>>(xa, xrs_b, xrd,
                                                      wpack + (size_t)8 * 16384, b_ln, feats);
  final_fc_kernel<<<1, 128, 0, stream>>>(feats, feats + 128, feats + 256, W_fc, b_fc, out);
}

// Round 15
// 593.652 us; speedup vs baseline: 1.2233x; 1.2233x over previous
//
#include <hip/hip_runtime.h>
#include <cmath>

#define HID 128

typedef __attribute__((ext_vector_type(8))) short bf16x8;
typedef __attribute__((ext_vector_type(4))) float f32x4;

__device__ inline unsigned short f2bf_rne(float f) {
  unsigned int b = __float_as_uint(f);
  return (unsigned short)((b + 0x7fffu + ((b >> 16) & 1u)) >> 16);
}
__device__ inline float bf2f(unsigned int u) { return __uint_as_float(u << 16); }

// dst-space: f:0 | rs:100000 | rd:120000 | hrd:170000 ; NDTOT=220000
#define NDTOT 220000
#define ETOT 4000000
#define BSH 8            // 256 dst per bucket
#define BDST 256
#define NB 860           // ceil(NDTOT/BDST)
#define BCAP 5376        // fixed bucket capacity (mean 4654, sigma 68 -> 10.6 sigma)
#define EPB 16384        // edges per binning block
#define NBINBLK 245      // ceil(ETOT/EPB)

// ---------------- utility kernels ----------------

// zero bfill[NB] and feats[384] in one launch
__global__ void fill_z_kernel(int* __restrict__ bfill, float* __restrict__ feats) {
  int i = blockIdx.x * 256 + threadIdx.x;
  if (i < NB) bfill[i] = 0;
  if (i < 384) feats[i] = 0.f;
}

// fp32 -> bf16 (RNE) for all three states in one launch; item = 8 floats
__global__ void f2bf_all_kernel(const float* __restrict__ xa, const float* __restrict__ xrs,
                                const float* __restrict__ xrd, unsigned short* __restrict__ oa,
                                unsigned short* __restrict__ ors, unsigned short* __restrict__ ord) {
  int i = blockIdx.x * 256 + threadIdx.x;
  const float* in; unsigned short* out; int li;
  if (i < 1600000)      { in = xa;  out = oa;  li = i; }
  else if (i < 1920000) { in = xrs; out = ors; li = i - 1600000; }
  else if (i < 2720000) { in = xrd; out = ord; li = i - 1920000; }
  else return;
  const float4* p4 = reinterpret_cast<const float4*>(in) + (size_t)li * 2;
  float4 v0 = p4[0], v1 = p4[1];
  float vv[8] = {v0.x, v0.y, v0.z, v0.w, v1.x, v1.y, v1.z, v1.w};
  unsigned int r[8];
#pragma unroll
  for (int j = 0; j < 8; ++j) r[j] = f2bf_rne(vv[j]);
  uint4 o;
  o.x = r[0] | (r[1] << 16);
  o.y = r[2] | (r[3] << 16);
  o.z = r[4] | (r[5] << 16);
  o.w = r[6] | (r[7] << 16);
  reinterpret_cast<uint4*>(out)[li] = o;
}

// pack 9 x 128x128 fp32 W (row-major [k][col]) into MFMA B-fragment order, bf16.
__global__ void pack_w_kernel(const float* __restrict__ Wsrc8, const float* __restrict__ W_ln,
                              unsigned short* __restrict__ Wp) {
  int g = blockIdx.y;
  const float* W = (g < 8) ? (Wsrc8 + (size_t)g * 16384) : W_ln;
  unsigned short* op = Wp + (size_t)g * 16384;
  int o = blockIdx.x * 256 + threadIdx.x;
  if (o >= 16384) return;
  int j = o & 7;
  int lane = (o >> 3) & 63;
  int kk = (o >> 9) & 3;
  int ct = (o >> 11) & 3;
  int half = (o >> 13) & 1;
  int k = kk * 32 + ((lane >> 4) * 8) + j;
  int col = half * 64 + ct * 16 + (lane & 15);
  op[o] = f2bf_rne(W[k * 128 + col]);
}

// v[g][k] = sum_c W[g][k][c] * a[g][c]; blockIdx.y: 0 -> (Wsrc,att_src,vs), 1 -> (Wdst,att_dst,vd)
__global__ void compute_v2_kernel(const float* __restrict__ Wsrc, const float* __restrict__ Wdst,
                                  const float* __restrict__ as_, const float* __restrict__ ad_,
                                  float* __restrict__ vs, float* __restrict__ vd) {
  int g = blockIdx.x, k = threadIdx.x;
  const float* W = (blockIdx.y ? Wdst : Wsrc) + g * 16384;
  const float* a = (blockIdx.y ? ad_ : as_) + g * 128;
  float* v = (blockIdx.y ? vd : vs) + g * 128;
  float s = 0.f;
  for (int c = 0; c < 128; ++c) s = fmaf(W[k * 128 + c], a[c], s);
  v[k] = s;
}

// ---------------- fused alpha matvec: all 8 dots, one pass over all states ----------------
__device__ inline const float* pick_vec(int r, const float* vs, const float* vd, int L) {
  switch (r) {
    case 0: return vs + (0 + L) * 128;   // af_s
    case 1: return vd + (0 + L) * 128;   // af_d
    case 2: return vs + (2 + L) * 128;   // ars_s
    case 3: return vs + (6 + L) * 128;   // ahrd_s
    case 4: return vs + (4 + L) * 128;   // ard_s
    case 5: return vd + (4 + L) * 128;   // ard_d
    case 6: return vd + (6 + L) * 128;   // ahrd_d
    default: return vd + (2 + L) * 128;  // ars_d
  }
}

__global__ __launch_bounds__(256) void matvec_fused_kernel(
    const unsigned short* __restrict__ xa, const unsigned short* __restrict__ xrd,
    const unsigned short* __restrict__ xrs, const float* __restrict__ vs,
    const float* __restrict__ vd, int L, float* __restrict__ af_s, float* __restrict__ af_d,
    float* __restrict__ ars_s, float* __restrict__ ahrd_s, float* __restrict__ ard_s,
    float* __restrict__ ard_d, float* __restrict__ ahrd_d, float* __restrict__ ars_d) {
  __shared__ float vl[11][128];
  int tid = threadIdx.x;
  for (int i = tid; i < 1024; i += 256) {
    int r = i >> 7;
    vl[r][i & 127] = pick_vec(r, vs, vd, L)[i & 127];
  }
  for (int i = tid; i < 384; i += 256) vl[8 + (i >> 7)][i & 127] = 0.f;
  __syncthreads();
  int wave = tid >> 6, lane = tid & 63;
  int sub = lane >> 4, li = lane & 15;
  int row = blockIdx.x * 16 + wave * 4 + sub;
  if (row >= 170000) return;
  const unsigned short* X; int lrow, vbase;
  if (row < 100000)      { X = xa;  lrow = row;          vbase = 0; }
  else if (row < 150000) { X = xrd; lrow = row - 100000; vbase = 4; }
  else                   { X = xrs; lrow = row - 150000; vbase = 7; }
  const uint4 xv = *reinterpret_cast<const uint4*>(X + (size_t)lrow * 128 + li * 8);
  float f[8];
  f[0] = bf2f(xv.x & 0xffffu); f[1] = bf2f(xv.x >> 16);
  f[2] = bf2f(xv.y & 0xffffu); f[3] = bf2f(xv.y >> 16);
  f[4] = bf2f(xv.z & 0xffffu); f[5] = bf2f(xv.z >> 16);
  f[6] = bf2f(xv.w & 0xffffu); f[7] = bf2f(xv.w >> 16);
  float a0 = 0.f, a1 = 0.f, a2 = 0.f, a3 = 0.f;
#pragma unroll
  for (int q = 0; q < 8; ++q) {
    int col = li * 8 + q;
    a0 = fmaf(f[q], vl[vbase][col], a0);
    a1 = fmaf(f[q], vl[vbase + 1][col], a1);
    a2 = fmaf(f[q], vl[vbase + 2][col], a2);
    a3 = fmaf(f[q], vl[vbase + 3][col], a3);
  }
#pragma unroll
  for (int off = 8; off >= 1; off >>= 1) {
    a0 += __shfl_xor(a0, off);
    a1 += __shfl_xor(a1, off);
    a2 += __shfl_xor(a2, off);
    a3 += __shfl_xor(a3, off);
  }
  if (li == 0) {
    if (row < 100000) {
      af_s[lrow] = a0; af_d[lrow] = a1; ars_s[lrow] = a2; ahrd_s[lrow] = a3;
    } else if (row < 150000) {
      ard_s[lrow] = a0; ard_d[lrow] = a1; ahrd_d[lrow] = a2;
    } else {
      ars_d[lrow] = a0;
    }
  }
}

// max|x| over 4 arrays; one block per array (blockIdx.x = y); plain store.
__global__ __launch_bounds__(256) void max4_kernel(
    const float* __restrict__ a0, const float* __restrict__ a1, const float* __restrict__ a2,
    const float* __restrict__ a3, int n0, int n1, int n2, int n3,
    unsigned int* __restrict__ outm) {
  __shared__ float red[256];
  int y = blockIdx.x, tid = threadIdx.x;
  const float* a = (y == 0) ? a0 : (y == 1) ? a1 : (y == 2) ? a2 : a3;
  int n4 = ((y == 0) ? n0 : (y == 1) ? n1 : (y == 2) ? n2 : n3) >> 2;
  float m = 0.f;
  const float4* a4 = reinterpret_cast<const float4*>(a);
  for (int i = tid; i < n4; i += 256) {
    float4 v = a4[i];
    m = fmaxf(m, fmaxf(fmaxf(fabsf(v.x), fabsf(v.y)), fmaxf(fabsf(v.z), fabsf(v.w))));
  }
  red[tid] = m;
  __syncthreads();
  for (int off = 128; off; off >>= 1) {
    if (tid < off) red[tid] = fmaxf(red[tid], red[tid + off]);
    __syncthreads();
  }
  if (tid == 0) outm[y] = __float_as_uint(red[0]);
}

// ---------------- CSR build: fixed-capacity buckets (no hist, no scan) ----------------

__device__ inline void decode_edge(int e, const int* __restrict__ s0, const int* __restrict__ d0,
                                   const int* __restrict__ s1, const int* __restrict__ d1,
                                   const int* __restrict__ s2, const int* __restrict__ d2,
                                   const int* __restrict__ s3, const int* __restrict__ d3,
                                   int& src, int& gd) {
  const int* sp; const int* dp; int base, doff;
  if (e < 1600000)      { sp = s0; dp = d0; base = 0;       doff = 0; }
  else if (e < 2400000) { sp = s1; dp = d1; base = 1600000; doff = 100000; }
  else if (e < 3200000) { sp = s2; dp = d2; base = 2400000; doff = 120000; }
  else                  { sp = s3; dp = d3; base = 3200000; doff = 170000; }
  int i = e - base;
  src = sp[i];
  gd = doff + dp[i];
}

// pass 1: scatter packed (local_dst<<24 | src) into fixed-capacity bucket regions
__global__ __launch_bounds__(256) void bin_scatter_kernel(
    const int* __restrict__ s0, const int* __restrict__ d0, const int* __restrict__ s1,
    const int* __restrict__ d1, const int* __restrict__ s2, const int* __restrict__ d2,
    const int* __restrict__ s3, const int* __restrict__ d3,
    int* __restrict__ bfill, unsigned int* __restrict__ pair_buf) {
  __shared__ int lh[NB];
  __shared__ int lbase[NB];
  for (int i = threadIdx.x; i < NB; i += 256) lh[i] = 0;
  __syncthreads();
  int e0 = blockIdx.x * EPB;
  for (int i = 0; i < EPB; i += 256) {
    int e = e0 + i + threadIdx.x;
    if (e < ETOT) {
      const int* dp; int base, doff;
      if (e < 1600000)      { dp = d0; base = 0;       doff = 0; }
      else if (e < 2400000) { dp = d1; base = 1600000; doff = 100000; }
      else if (e < 3200000) { dp = d2; base = 2400000; doff = 120000; }
      else                  { dp = d3; base = 3200000; doff = 170000; }
      atomicAdd(&lh[(doff + dp[e - base]) >> BSH], 1);
    }
  }
  __syncthreads();
  for (int i = threadIdx.x; i < NB; i += 256) {
    int c = lh[i];
    if (c) lbase[i] = i * BCAP + atomicAdd(&bfill[i], c);
    lh[i] = 0;  // reuse as cursor
  }
  __syncthreads();
  for (int i = 0; i < EPB; i += 256) {
    int e = e0 + i + threadIdx.x;
    if (e < ETOT) {
      int src, gd;
      decode_edge(e, s0, d0, s1, d1, s2, d2, s3, d3, src, gd);
      int b = gd >> BSH;
      int pos = atomicAdd(&lh[b], 1);
      pair_buf[lbase[b] + pos] = ((unsigned)(gd & (BDST - 1)) << 24) | (unsigned)src;
    }
  }
}

// pass 2: per-bucket — local hist/scan builds rbeg/rend, then in-window scatter
__global__ __launch_bounds__(256) void bucket_build_kernel(
    const unsigned int* __restrict__ pair_buf, const int* __restrict__ bfill,
    int* __restrict__ rbeg, int* __restrict__ rend, int* __restrict__ csr_cat) {
  __shared__ int lcnt[BDST];
  __shared__ int lrp[BDST + 1];
  int b = blockIdx.x;
  int d0 = b << BSH;
  int nd = min(BDST, NDTOT - d0);
  int base = b * BCAP, end = base + bfill[b];
  for (int i = threadIdx.x; i < nd; i += 256) lcnt[i] = 0;
  __syncthreads();
  for (int j = base + threadIdx.x; j < end; j += 256)
    atomicAdd(&lcnt[pair_buf[j] >> 24], 1);
  __syncthreads();
  if (threadIdx.x == 0) {
    int run = base;
    for (int i = 0; i < nd; ++i) { lrp[i] = run; run += lcnt[i]; }
    lrp[nd] = run;
  }
  __syncthreads();
  for (int i = threadIdx.x; i < nd; i += 256) {
    rbeg[d0 + i] = lrp[i];
    rend[d0 + i] = lrp[i + 1];
  }
  for (int i = threadIdx.x; i < nd; i += 256) lcnt[i] = 0;
  __syncthreads();
  for (int j = base + threadIdx.x; j < end; j += 256) {
    unsigned int pr = pair_buf[j];
    int ld = pr >> 24;
    int pos = lrp[ld] + atomicAdd(&lcnt[ld], 1);
    csr_cat[pos] = (int)(pr & 0xFFFFFFu);
  }
}

// ---------------- fused GAT aggregation, 4-deep pipelined gather (R10/R12 proven) ----------------
// p = exp(e - mhat), mhat = lrelu(max|as| + ad[d]) >= all e
#define ACC8(xv, wgt)                                   \
  do {                                                  \
    a[0] = fmaf(wgt, bf2f((xv).x & 0xffffu), a[0]);     \
    a[1] = fmaf(wgt, bf2f((xv).x >> 16), a[1]);         \
    a[2] = fmaf(wgt, bf2f((xv).y & 0xffffu), a[2]);     \
    a[3] = fmaf(wgt, bf2f((xv).y >> 16), a[3]);         \
    a[4] = fmaf(wgt, bf2f((xv).z & 0xffffu), a[4]);     \
    a[5] = fmaf(wgt, bf2f((xv).z >> 16), a[5]);         \
    a[6] = fmaf(wgt, bf2f((xv).w & 0xffffu), a[6]);     \
    a[7] = fmaf(wgt, bf2f((xv).w >> 16), a[7]);         \
  } while (0)

__global__ __launch_bounds__(256) void gat_aggr_fused(
    const int* __restrict__ rbeg, const int* __restrict__ rend,
    const int* __restrict__ csr_cat,
    const float* __restrict__ af_s, const float* __restrict__ af_d,
    const float* __restrict__ ars_s, const float* __restrict__ ars_d,
    const float* __restrict__ ard_s, const float* __restrict__ ard_d,
    const float* __restrict__ ahrd_s, const float* __restrict__ ahrd_d,
    const unsigned int* __restrict__ asmax, const unsigned short* __restrict__ xa,
    const unsigned short* __restrict__ xrd, unsigned short* __restrict__ aggh) {
  __shared__ float2 sp[4][64];
  int wave = threadIdx.x >> 6, lane = threadIdx.x & 63;
  int g = lane >> 4, li = lane & 15;
  int gd = blockIdx.x * 4 + wave;
  if (gd >= NDTOT) return;
  const float* as_; const float* ad_; const unsigned short* Xh; int midx, d;
  if (gd < 100000)      { as_ = af_s;  ad_ = af_d;  Xh = xa;  midx = 0; d = gd; }
  else if (gd < 120000) { as_ = ars_s; ad_ = ars_d; Xh = xa;  midx = 1; d = gd - 100000; }
  else if (gd < 170000) { as_ = ard_s; ad_ = ard_d; Xh = xrd; midx = 3; d = gd - 120000; }
  else                  { as_ = ahrd_s; ad_ = ahrd_d; Xh = xa; midx = 2; d = gd - 170000; }
  int beg = rbeg[gd], end = rend[gd];
  float ad = ad_[d];
  float t0 = __uint_as_float(asmax[midx]) + ad;
  float mh = t0 > 0.f ? t0 : 0.2f * t0;
  float z = 0.f;
  float a[8] = {};
  for (int c0 = beg; c0 < end; c0 += 64) {
    int j = c0 + lane;
    int s = 0;
    float p = 0.f;
    if (j < end) {
      s = csr_cat[j];
      float t = as_[s] + ad;
      float e = t > 0.f ? t : 0.2f * t;
      p = __expf(e - mh);
      z += p;
    }
    sp[wave][lane] = make_float2(__int_as_float(s), p);
    asm volatile("s_waitcnt lgkmcnt(0)" ::: "memory");
    int cnt = min(64, end - c0);
    // subgroup g handles edges g, g+4, g+8, ... ; 4 edges pipelined per iter
    for (int k = g; k < cnt; k += 16) {
      float2 w0 = sp[wave][k];
      float2 w1 = (k + 4 < cnt) ? sp[wave][k + 4] : make_float2(0.f, 0.f);
      float2 w2 = (k + 8 < cnt) ? sp[wave][k + 8] : make_float2(0.f, 0.f);
      float2 w3 = (k + 12 < cnt) ? sp[wave][k + 12] : make_float2(0.f, 0.f);
      // masked edges -> row 0 with weight 0 (branch-free, safe)
      const uint4 x0 = *reinterpret_cast<const uint4*>(
          Xh + (size_t)(unsigned)__float_as_int(w0.x) * 128 + li * 8);
      const uint4 x1 = *reinterpret_cast<const uint4*>(
          Xh + (size_t)(unsigned)__float_as_int(w1.x) * 128 + li * 8);
      const uint4 x2 = *reinterpret_cast<const uint4*>(
          Xh + (size_t)(unsigned)__float_as_int(w2.x) * 128 + li * 8);
      const uint4 x3 = *reinterpret_cast<const uint4*>(
          Xh + (size_t)(unsigned)__float_as_int(w3.x) * 128 + li * 8);
      ACC8(x0, w0.y);
      ACC8(x1, w1.y);
      ACC8(x2, w2.y);
      ACC8(x3, w3.y);
    }
  }
#pragma unroll
  for (int off = 32; off >= 1; off >>= 1) z += __shfl_xor(z, off);
#pragma unroll
  for (int i = 0; i < 8; ++i) {
    a[i] += __shfl_xor(a[i], 32);
    a[i] += __shfl_xor(a[i], 16);
  }
  if (g == 0) {
    float inv = 1.f / fmaxf(z, 1e-16f);
    uint4 o;
    o.x = (unsigned)f2bf_rne(a[0] * inv) | ((unsigned)f2bf_rne(a[1] * inv) << 16);
    o.y = (unsigned)f2bf_rne(a[2] * inv) | ((unsigned)f2bf_rne(a[3] * inv) << 16);
    o.z = (unsigned)f2bf_rne(a[4] * inv) | ((unsigned)f2bf_rne(a[5] * inv) << 16);
    o.w = (unsigned)f2bf_rne(a[6] * inv) | ((unsigned)f2bf_rne(a[7] * inv) << 16);
    *reinterpret_cast<uint4*>(aggh + (size_t)gd * 128 + li * 8) = o;
  }
}

// ---------------- fused MFMA GEMM over the 3 per-layer GEMMs ----------------
// blocks: [0,782) act | [782,939) rs | [939,1330) rd (two-input K=256)
__global__ __launch_bounds__(256) void gemm_all_kernel(
    const unsigned short* __restrict__ aggh, const unsigned short* __restrict__ wpack,
    const float* __restrict__ b_gat, int L, unsigned short* __restrict__ ya,
    unsigned short* __restrict__ yrs, unsigned short* __restrict__ yrd) {
  int bx = blockIdx.x;
  const unsigned short *X1, *X2 = nullptr, *Wp1, *Wp2 = nullptr;
  const float *bias1, *bias2 = nullptr;
  unsigned short* Y;
  int N, r0;
  if (bx < 782) {
    int gg = 0 + L;
    X1 = aggh; Wp1 = wpack + (size_t)gg * 16384; bias1 = b_gat + gg * 128;
    Y = ya; N = 100000; r0 = bx * 128;
  } else if (bx < 939) {
    int gg = 2 + L;
    X1 = aggh + (size_t)100000 * 128; Wp1 = wpack + (size_t)gg * 16384;
    bias1 = b_gat + gg * 128;
    Y = yrs; N = 20000; r0 = (bx - 782) * 128;
  } else {
    int g2 = 4 + L, g3 = 6 + L;
    X1 = aggh + (size_t)120000 * 128; Wp1 = wpack + (size_t)g2 * 16384;
    bias1 = b_gat + g2 * 128;
    X2 = aggh + (size_t)170000 * 128; Wp2 = wpack + (size_t)g3 * 16384;
    bias2 = b_gat + g3 * 128;
    Y = yrd; N = 50000; r0 = (bx - 939) * 128;
  }
  int wid = threadIdx.x >> 6, lane = threadIdx.x & 63;
  int half = blockIdx.y;
  int rr0 = r0 + wid * 32;
  int lr = lane & 15, gk = lane >> 4;
  f32x4 acc[2][4];
#pragma unroll
  for (int rt = 0; rt < 2; ++rt)
#pragma unroll
    for (int ct = 0; ct < 4; ++ct) acc[rt][ct] = (f32x4){0.f, 0.f, 0.f, 0.f};
  int row0 = rr0 + lr, row1 = rr0 + 16 + lr;
  int nph = X2 ? 2 : 1;
  for (int ph = 0; ph < nph; ++ph) {
    const unsigned short* X = ph ? X2 : X1;
    const unsigned short* Wp = ph ? Wp2 : Wp1;
    bf16x8 b[4][4];
#pragma unroll
    for (int ct = 0; ct < 4; ++ct)
#pragma unroll
      for (int kk = 0; kk < 4; ++kk)
        b[ct][kk] = *reinterpret_cast<const bf16x8*>(Wp + ((((half * 4 + ct) * 4 + kk) * 64 + lane) << 3));
#pragma unroll
    for (int kk = 0; kk < 4; ++kk) {
      bf16x8 a0 = {}, a1 = {};
      if (row0 < N) a0 = *reinterpret_cast<const bf16x8*>(X + (size_t)row0 * 128 + kk * 32 + gk * 8);
      if (row1 < N) a1 = *reinterpret_cast<const bf16x8*>(X + (size_t)row1 * 128 + kk * 32 + gk * 8);
#pragma unroll
      for (int ct = 0; ct < 4; ++ct) {
        acc[0][ct] = __builtin_amdgcn_mfma_f32_16x16x32_bf16(a0, b[ct][kk], acc[0][ct], 0, 0, 0);
        acc[1][ct] = __builtin_amdgcn_mfma_f32_16x16x32_bf16(a1, b[ct][kk], acc[1][ct], 0, 0, 0);
      }
    }
  }
#pragma unroll
  for (int rt = 0; rt < 2; ++rt)
#pragma unroll
    for (int ct = 0; ct < 4; ++ct) {
      int col = half * 64 + ct * 16 + lr;
      float bcol = bias1[col] + (bias2 ? bias2[col] : 0.f);
#pragma unroll
      for (int reg = 0; reg < 4; ++reg) {
        int row = rr0 + rt * 16 + gk * 4 + reg;
        if (row < N) {
          float o = acc[rt][ct][reg] + bcol;
          Y[(size_t)row * 128 + col] = f2bf_rne(fmaxf(o, 0.f));
        }
      }
    }
}

// ---------------- fused MFMA head over the 3 node types ----------------
__global__ __launch_bounds__(256) void head_fused_kernel(
    const unsigned short* __restrict__ xa, const unsigned short* __restrict__ xrs,
    const unsigned short* __restrict__ xrd, const unsigned short* __restrict__ Wp,
    const float* __restrict__ bias, float* __restrict__ feat) {
  __shared__ float cs[64];
  int bx = blockIdx.x;
  const unsigned short* X; float* f; int N, bx0;
  if (bx < 196)      { X = xa;  f = feat;       N = 100000; bx0 = bx; }
  else if (bx < 236) { X = xrs; f = feat + 128; N = 20000;  bx0 = bx - 196; }
  else               { X = xrd; f = feat + 256; N = 50000;  bx0 = bx - 236; }
  int wid = threadIdx.x >> 6, lane = threadIdx.x & 63;
  int half = blockIdx.y;
  int lr = lane & 15, gk = lane >> 4;
  if (threadIdx.x < 64) cs[threadIdx.x] = 0.f;
  __syncthreads();
  bf16x8 b[4][4];
#pragma unroll
  for (int ct = 0; ct < 4; ++ct)
#pragma unroll
    for (int kk = 0; kk < 4; ++kk)
      b[ct][kk] = *reinterpret_cast<const bf16x8*>(Wp + ((((half * 4 + ct) * 4 + kk) * 64 + lane) << 3));
  float colsum[4] = {0.f, 0.f, 0.f, 0.f};
  for (int c = 0; c < 4; ++c) {
    int r0 = bx0 * 512 + c * 128 + wid * 32;
    if (r0 >= N) break;
    f32x4 acc[2][4];
#pragma unroll
    for (int rt = 0; rt < 2; ++rt)
#pragma unroll
      for (int ct = 0; ct < 4; ++ct) acc[rt][ct] = (f32x4){0.f, 0.f, 0.f, 0.f};
    int row0 = r0 + lr, row1 = r0 + 16 + lr;
#pragma unroll
    for (int kk = 0; kk < 4; ++kk) {
      bf16x8 a0 = {}, a1 = {};
      if (row0 < N) a0 = *reinterpret_cast<const bf16x8*>(X + (size_t)row0 * 128 + kk * 32 + gk * 8);
      if (row1 < N) a1 = *reinterpret_cast<const bf16x8*>(X + (size_t)row1 * 128 + kk * 32 + gk * 8);
#pragma unroll
      for (int ct = 0; ct < 4; ++ct) {
        acc[0][ct] = __builtin_amdgcn_mfma_f32_16x16x32_bf16(a0, b[ct][kk], acc[0][ct], 0, 0, 0);
        acc[1][ct] = __builtin_amdgcn_mfma_f32_16x16x32_bf16(a1, b[ct][kk], acc[1][ct], 0, 0, 0);
      }
    }
#pragma unroll
    for (int rt = 0; rt < 2; ++rt)
#pragma unroll
      for (int ct = 0; ct < 4; ++ct) {
        float bcol = bias[half * 64 + ct * 16 + lr];
#pragma unroll
        for (int reg = 0; reg < 4; ++reg) {
          int row = r0 + rt * 16 + gk * 4 + reg;
          if (row < N) colsum[ct] += fmaxf(acc[rt][ct][reg] + bcol, 0.f);
        }
      }
  }
#pragma unroll
  for (int ct = 0; ct < 4; ++ct) {
    float v = colsum[ct];
    v += __shfl_xor(v, 16);
    v += __shfl_xor(v, 32);
    if (gk == 0) atomicAdd(&cs[ct * 16 + lr], v);
  }
  __syncthreads();
  if (threadIdx.x < 64) atomicAdd(&f[half * 64 + threadIdx.x], cs[threadIdx.x]);
}

__global__ void final_fc_kernel(const float* __restrict__ fa, const float* __restrict__ frs,
                                const float* __restrict__ frd, const float* __restrict__ Wfc,
                                const float* __restrict__ bfc, float* __restrict__ out) {
  __shared__ float pooled[128];
  int t = threadIdx.x;
  if (t < 128)
    pooled[t] = (fa[t] * (1.f / 100000.f) + frs[t] * (1.f / 20000.f) + frd[t] * (1.f / 50000.f)) *
                (1.f / 3.f);
  __syncthreads();
  if (t < 64) {
    float s = bfc[t];
    for (int c = 0; c < 128; ++c) s = fmaf(pooled[c], Wfc[c * 64 + t], s);
    out[t] = s;
  }
}

// ---------------- orchestration ----------------

extern "C" void kernel_launch(void* const* d_in, const int* in_sizes, int n_in,
                              void* d_out, int out_size, void* d_ws, size_t ws_size,
                              hipStream_t stream) {
  const int N_ACT = 100000, N_RS = 20000, N_RD = 50000;

  const float* x_act = (const float*)d_in[0];
  const float* x_rs = (const float*)d_in[1];
  const float* x_rd = (const float*)d_in[2];
  const int* ef_src = (const int*)d_in[3];
  const int* ef_dst = (const int*)d_in[4];
  const int* ers_src = (const int*)d_in[5];
  const int* ers_dst = (const int*)d_in[6];
  const int* erd_src = (const int*)d_in[7];
  const int* erd_dst = (const int*)d_in[8];
  const int* ehrd_src = (const int*)d_in[9];
  const int* ehrd_dst = (const int*)d_in[10];
  const float* Wsrc = (const float*)d_in[11];
  const float* Wdst = (const float*)d_in[12];
  const float* att_src = (const float*)d_in[13];
  const float* att_dst = (const float*)d_in[14];
  const float* b_gat = (const float*)d_in[15];
  const float* W_ln = (const float*)d_in[16];
  const float* b_ln = (const float*)d_in[17];
  const float* W_fc = (const float*)d_in[18];
  const float* b_fc = (const float*)d_in[19];
  float* out = (float*)d_out;

  // ---- workspace layout (~175 MB) ----
  float* w = (float*)d_ws;
  float* af_s = w;   w += N_ACT;
  float* af_d = w;   w += N_ACT;
  float* ars_s = w;  w += N_ACT;
  float* ahrd_s = w; w += N_ACT;
  float* ard_s = w;  w += N_RD;
  float* ard_d = w;  w += N_RD;
  float* ahrd_d = w; w += N_RD;
  float* ars_d = w;  w += N_RS;
  float* vs = w;    w += 1024;
  float* vd = w;    w += 1024;
  float* feats = w; w += 384;
  unsigned int* asmax_u = (unsigned int*)w; w += 16;
  unsigned short* xa0 = (unsigned short*)w;   w += (size_t)N_ACT * 64;
  unsigned short* xa1 = (unsigned short*)w;   w += (size_t)N_ACT * 64;
  unsigned short* xrd0 = (unsigned short*)w;  w += (size_t)N_RD * 64;
  unsigned short* xrd1 = (unsigned short*)w;  w += (size_t)N_RD * 64;
  unsigned short* xrs_b = (unsigned short*)w; w += (size_t)N_RS * 64;
  unsigned short* aggh = (unsigned short*)w;  w += (size_t)NDTOT * 64;  // concat agg
  unsigned short* wpack = (unsigned short*)w; w += (9 * 16384) / 2;
  int* ip = (int*)w;
  unsigned int* pair_buf = (unsigned int*)ip; ip += NB * BCAP;  // packed (ld<<24)|src
  int* csr_cat = ip;          ip += NB * BCAP;
  int* rbeg = ip;             ip += NDTOT;
  int* rend = ip;             ip += NDTOT;
  int* bfill = ip;            ip += NB;

  // ---- init + CSR build: fixed-capacity buckets ----
  fill_z_kernel<<<(NB + 255) / 256, 256, 0, stream>>>(bfill, feats);
  bin_scatter_kernel<<<NBINBLK, 256, 0, stream>>>(
      ef_src, ef_dst, ers_src, ers_dst, erd_src, erd_dst, ehrd_src, ehrd_dst,
      bfill, pair_buf);
  bucket_build_kernel<<<NB, 256, 0, stream>>>(pair_buf, bfill, rbeg, rend, csr_cat);

  // ---- one-time: attention vectors, packed weights, bf16 states ----
  compute_v2_kernel<<<dim3(8, 2), 128, 0, stream>>>(Wsrc, Wdst, att_src, att_dst, vs, vd);
  pack_w_kernel<<<dim3(64, 9), 256, 0, stream>>>(Wsrc, W_ln, wpack);
  f2bf_all_kernel<<<(2720000 + 255) / 256, 256, 0, stream>>>(x_act, x_rs, x_rd,
                                                             xa0, xrs_b, xrd0);

  const unsigned short* xa = xa0;
  unsigned short* xa_nxt = xa1;
  const unsigned short* xrd = xrd0;
  unsigned short* xrd_nxt = xrd1;

  for (int L = 0; L < 2; ++L) {
    matvec_fused_kernel<<<(170000 + 15) / 16, 256, 0, stream>>>(
        xa, xrd, xrs_b, vs, vd, L, af_s, af_d, ars_s, ahrd_s, ard_s, ard_d, ahrd_d, ars_d);

    max4_kernel<<<4, 256, 0, stream>>>(af_s, ars_s, ahrd_s, ard_s,
                                       N_ACT, N_ACT, N_ACT, N_RD, asmax_u);

    gat_aggr_fused<<<(NDTOT + 3) / 4, 256, 0, stream>>>(
        rbeg, rend, csr_cat, af_s, af_d, ars_s, ars_d, ard_s, ard_d, ahrd_s, ahrd_d,
        asmax_u, xa, xrd, aggh);

    gemm_all_kernel<<<dim3(1330, 2), 256, 0, stream>>>(aggh, wpack, b_gat, L,
                                                       xa_nxt, xrs_b, xrd_nxt);

    const unsigned short* t1 = xa; xa = xa_nxt; xa_nxt = (unsigned short*)t1;
    const unsigned short* t2 = xrd; xrd = xrd_nxt; xrd_nxt = (unsigned short*)t2;
  }

  head_fused_kernel<<<dim3(334, 2), 256, 0, stream>>>(xa, xrs_b, xrd,
                                                      wpack + (size_t)8 * 16384, b_ln, feats);
  final_fc_kernel<<<1, 128, 0, stream>>>(feats, feats + 128, feats + 256, W_fc, b_fc, out);
}